// Round 1
// baseline (899.983 us; speedup 1.0000x reference)
//
#include <hip/hip_runtime.h>
#include <hip/hip_bf16.h>

// Problem constants (from reference)
#define NNODE 25000
#define PEDGE 400000
#define FDIM  224      // F = TF = 224; q/k: 7 heads x 32, v: 4 heads x 56
#define NORD  15
#define NXOUT (NNODE*FDIM)

typedef __bf16 bf16x8 __attribute__((ext_vector_type(8)));
typedef short  s16x8  __attribute__((ext_vector_type(8)));
typedef float  f32x4  __attribute__((ext_vector_type(4)));

// MFMA wrapper: tolerate either v8bf16 or v8i16 builtin signature across ROCm versions.
template <typename V>
__device__ __forceinline__ auto mfma_impl(V a, V b, f32x4 c, int)
    -> decltype(__builtin_amdgcn_mfma_f32_16x16x32_bf16(a, b, c, 0, 0, 0)) {
  return __builtin_amdgcn_mfma_f32_16x16x32_bf16(a, b, c, 0, 0, 0);
}
template <typename V>
__device__ __forceinline__ f32x4 mfma_impl(V a, V b, f32x4 c, long) {
  return __builtin_amdgcn_mfma_f32_16x16x32_bf16(
      __builtin_bit_cast(s16x8, a), __builtin_bit_cast(s16x8, b), c, 0, 0, 0);
}
__device__ __forceinline__ f32x4 MFMA_BF16(bf16x8 a, bf16x8 b, f32x4 c) {
  return mfma_impl(a, b, c, 0);
}

__device__ __forceinline__ float siluf(float x) { return x / (1.0f + __expf(-x)); }
__device__ __forceinline__ unsigned short f2bf(float x) {
  __hip_bfloat16 h = __float2bfloat16(x);
  return __builtin_bit_cast(unsigned short, h);
}
__device__ __forceinline__ float bf2f(unsigned short u) {
  unsigned int v = ((unsigned int)u) << 16;
  return __builtin_bit_cast(float, v);
}

// ---------------------------------------------------------------------------
// k_pre: (a) node q,k,v projections -> bf16 tables; (b) CSR row_start from
// sorted idx_i; (c) W1cat (64x224 zero-padded block-diagonal) -> swizzled bf16.
// ---------------------------------------------------------------------------
__global__ __launch_bounds__(256) void k_pre(
    const float* __restrict__ x, const float* __restrict__ Wq,
    const float* __restrict__ Wk, const float* __restrict__ Wv,
    const int* __restrict__ idx_i,
    const float* __restrict__ W1r, const float* __restrict__ W1s,
    unsigned short* __restrict__ q_ws, unsigned short* __restrict__ k_ws,
    unsigned short* __restrict__ v_ws, int* __restrict__ rs,
    unsigned short* __restrict__ W1sw) {
  int b = blockIdx.x, t = threadIdx.x;
  __shared__ float xs[FDIM];
  if (b < NNODE) {
    if (t < FDIM) xs[t] = x[b*FDIM + t];
    __syncthreads();
    if (t < FDIM) {
      const float4* wq4 = (const float4*)(Wq + t*32);
      const float4* wk4 = (const float4*)(Wk + t*32);
      const float4* xh4 = (const float4*)(xs + ((t>>5)<<5));
      float aq = 0.f, ak = 0.f;
      #pragma unroll
      for (int j = 0; j < 8; j++) {
        float4 xv = xh4[j];
        float4 a = wq4[j]; aq += a.x*xv.x + a.y*xv.y + a.z*xv.z + a.w*xv.w;
        float4 bb = wk4[j]; ak += bb.x*xv.x + bb.y*xv.y + bb.z*xv.z + bb.w*xv.w;
      }
      q_ws[b*FDIM + t] = f2bf(siluf(aq));
      k_ws[b*FDIM + t] = f2bf(siluf(ak));
      int h = t / 56, d = t - h*56;
      const float4* wv4 = (const float4*)(Wv + (h*56 + d)*56);
      const float4* xv4 = (const float4*)(xs + h*56);
      float av = 0.f;
      #pragma unroll
      for (int j = 0; j < 14; j++) {
        float4 a = wv4[j]; float4 xv = xv4[j];
        av += a.x*xv.x + a.y*xv.y + a.z*xv.z + a.w*xv.w;
      }
      v_ws[b*FDIM + t] = f2bf(av);  // no silu on v
    }
  } else if (b < NNODE + 1563) {
    int p = (b - NNODE)*256 + t;
    if (p < PEDGE) {
      int cur = idx_i[p];
      if (p == 0) { for (int v = 0; v <= cur; v++) rs[v] = 0; }
      else { int prev = idx_i[p-1]; for (int v = prev+1; v <= cur; v++) rs[v] = p; }
      if (p == PEDGE-1) { for (int v = cur+1; v <= NNODE; v++) rs[v] = PEDGE; }
    }
  } else {
    for (int lin = t; lin < 64*224; lin += 256) {
      int row = lin / 224, col = lin - row*224;
      float v = 0.f;
      if (col < 112) { if (row < 32) v = W1r[row*112 + col]; }
      else if (row >= 32 && row < 35) v = W1s[(row-32)*112 + (col-112)];
      int nt = col >> 4, lanelo = col & 15, k = row >> 5, hi = (row >> 3) & 3, j = row & 7;
      W1sw[(((nt*2 + k)*64) + hi*16 + lanelo)*8 + j] = f2bf(v);
    }
  }
}

// ---------------------------------------------------------------------------
// k_edge: fused edge MLP (layer1 K=64-padded, layer2 K=224, W2cat in LDS) +
// alpha = sum_head(q_i*w*k_j)*cut. 256 persistent blocks (1/CU). Each wave
// owns 32 edges; no barriers inside the tile loop (same-wave h1 RAW only).
// ---------------------------------------------------------------------------
__global__ __launch_bounds__(256) void k_edge(
    const float* __restrict__ rbf, const float* __restrict__ cut,
    const float* __restrict__ ev,
    const int* __restrict__ idx_i, const int* __restrict__ idx_j,
    const unsigned short* __restrict__ W1sw,
    const float* __restrict__ b1r, const float* __restrict__ b1s,
    const float* __restrict__ W2r, const float* __restrict__ W2s,
    const float* __restrict__ b2r, const float* __restrict__ b2s,
    const unsigned short* __restrict__ q_ws, const unsigned short* __restrict__ k_ws,
    float* __restrict__ alpha_ws) {
  __shared__ __bf16 W2sw[224*224];   // 100,352 B swizzled
  __shared__ __bf16 h1s[128*232];    // 59,392 B (+8 elem pad: aligned rows, benign banks)
  int tid = threadIdx.x;
  for (int lin = tid; lin < 224*224; lin += 256) {
    float v = (lin < 112*224) ? W2r[lin] : W2s[lin - 112*224];  // W2cat = [W2r; W2s]
    int row = lin / 224, col = lin - row*224;
    int nt = col >> 4, lanelo = col & 15, k = row >> 5, hi = (row >> 3) & 3, j = row & 7;
    W2sw[(((nt*7 + k)*64) + hi*16 + lanelo)*8 + j] = (__bf16)v;
  }
  __syncthreads();
  int wave = tid >> 6, lane = tid & 63;
  int mrow = lane & 15, quad = lane >> 4;
  for (int T = blockIdx.x; T < PEDGE/128; T += gridDim.x) {
    int base = T*128 + wave*32;
    bf16x8 u0[2], u1[2];
    #pragma unroll
    for (int mg = 0; mg < 2; mg++) {
      int e = base + mg*16 + mrow;
      float cu = cut[e];
      const float4* r4 = (const float4*)(rbf + e*32 + quad*8);
      float4 v0 = r4[0], v1 = r4[1];
      u0[mg][0] = (__bf16)(v0.x*cu); u0[mg][1] = (__bf16)(v0.y*cu);
      u0[mg][2] = (__bf16)(v0.z*cu); u0[mg][3] = (__bf16)(v0.w*cu);
      u0[mg][4] = (__bf16)(v1.x*cu); u0[mg][5] = (__bf16)(v1.y*cu);
      u0[mg][6] = (__bf16)(v1.z*cu); u0[mg][7] = (__bf16)(v1.w*cu);
      #pragma unroll
      for (int j = 0; j < 8; j++) u1[mg][j] = (__bf16)0.f;
      if (quad == 0) {
        int ie = idx_i[e], je = idx_j[e];
        const float* evi = ev + ie*NORD; const float* evj = ev + je*NORD;
        float s0 = 0.f, s1 = 0.f, s2 = 0.f;
        #pragma unroll
        for (int o = 0; o < 3; o++) { float d = evj[o]-evi[o]; s0 += d*d; }
        #pragma unroll
        for (int o = 3; o < 8; o++) { float d = evj[o]-evi[o]; s1 += d*d; }
        #pragma unroll
        for (int o = 8; o < 15; o++){ float d = evj[o]-evi[o]; s2 += d*d; }
        u1[mg][0] = (__bf16)s0; u1[mg][1] = (__bf16)s1; u1[mg][2] = (__bf16)s2;
      }
    }
    #pragma unroll
    for (int nt = 0; nt < 14; nt++) {
      bf16x8 b0 = *(const bf16x8*)(W1sw + ((nt*2 + 0)*64 + lane)*8);
      bf16x8 b1 = *(const bf16x8*)(W1sw + ((nt*2 + 1)*64 + lane)*8);
      int colg = nt*16 + mrow;
      float bias = (colg < 112) ? b1r[colg] : b1s[colg - 112];
      #pragma unroll
      for (int mg = 0; mg < 2; mg++) {
        f32x4 acc = {0.f, 0.f, 0.f, 0.f};
        acc = MFMA_BF16(u0[mg], b0, acc);
        acc = MFMA_BF16(u1[mg], b1, acc);
        int rowb = wave*32 + mg*16 + quad*4;
        #pragma unroll
        for (int r = 0; r < 4; r++)
          h1s[(rowb + r)*232 + colg] = (__bf16)siluf(acc[r] + bias);
      }
    }
    bf16x8 aa[2][7];
    #pragma unroll
    for (int mg = 0; mg < 2; mg++) {
      int rowa = wave*32 + mg*16 + mrow;
      #pragma unroll
      for (int k = 0; k < 7; k++)
        aa[mg][k] = *(const bf16x8*)&h1s[rowa*232 + k*32 + quad*8];
    }
    int ii[2][4], jj[2][4]; float cc[2][4];
    #pragma unroll
    for (int mg = 0; mg < 2; mg++)
      #pragma unroll
      for (int r = 0; r < 4; r++) {
        int e = base + mg*16 + quad*4 + r;
        ii[mg][r] = idx_i[e]; jj[mg][r] = idx_j[e]; cc[mg][r] = cut[e];
      }
    #pragma unroll
    for (int h = 0; h < 7; h++) {
      float part0[4] = {0.f,0.f,0.f,0.f}, part1[4] = {0.f,0.f,0.f,0.f};
      #pragma unroll
      for (int t2 = 0; t2 < 2; t2++) {
        int nt = h*2 + t2;
        f32x4 acc0 = {0.f,0.f,0.f,0.f}, acc1 = {0.f,0.f,0.f,0.f};
        #pragma unroll
        for (int k = 0; k < 7; k++) {
          bf16x8 bb = *(const bf16x8*)&W2sw[((nt*7 + k)*64 + lane)*8];
          acc0 = MFMA_BF16(aa[0][k], bb, acc0);
          acc1 = MFMA_BF16(aa[1][k], bb, acc1);
        }
        int colg = nt*16 + mrow;
        float bias = b2r[colg] + b2s[colg];
        #pragma unroll
        for (int r = 0; r < 4; r++) {
          float w0 = acc0[r] + bias;
          float w1 = acc1[r] + bias;
          part0[r] += bf2f(q_ws[ii[0][r]*FDIM + colg]) * w0 * bf2f(k_ws[jj[0][r]*FDIM + colg]);
          part1[r] += bf2f(q_ws[ii[1][r]*FDIM + colg]) * w1 * bf2f(k_ws[jj[1][r]*FDIM + colg]);
        }
      }
      #pragma unroll
      for (int r = 0; r < 4; r++) {
        float v0 = part0[r], v1 = part1[r];
        v0 += __shfl_xor(v0, 1); v0 += __shfl_xor(v0, 2);
        v0 += __shfl_xor(v0, 4); v0 += __shfl_xor(v0, 8);
        v1 += __shfl_xor(v1, 1); v1 += __shfl_xor(v1, 2);
        v1 += __shfl_xor(v1, 4); v1 += __shfl_xor(v1, 8);
        if (mrow == 0) {
          alpha_ws[(base + quad*4 + r)*7 + h]      = v0 * cc[0][r];
          alpha_ws[(base + 16 + quad*4 + r)*7 + h] = v1 * cc[1][r];
        }
      }
    }
  }
}

// ---------------------------------------------------------------------------
// k_agg: per-node segment sums -> outputs (zeros for empty segments, so the
// poisoned d_out is fully overwritten every call).
// ---------------------------------------------------------------------------
__global__ __launch_bounds__(256) void k_agg(
    const float* __restrict__ alpha_ws, const unsigned short* __restrict__ v_ws,
    const float* __restrict__ ylm, const int* __restrict__ idx_j,
    const int* __restrict__ rs, float* __restrict__ out) {
  int n = blockIdx.x, t = threadIdx.x;
  int s = rs[n], e = rs[n+1];
  if (t < FDIM) {
    int h = t / 56;
    float acc = 0.f;
    for (int p = s; p < e; p++)
      acc += alpha_ws[p*7 + h] * bf2f(v_ws[idx_j[p]*FDIM + t]);
    out[n*FDIM + t] = acc;
  } else if (t < FDIM + NORD) {
    int o = t - FDIM;
    int dg = (o < 3) ? 0 : ((o < 8) ? 1 : 2);
    float acc = 0.f;
    for (int p = s; p < e; p++)
      acc += alpha_ws[p*7 + 4 + dg] * ylm[p*NORD + o];
    out[NXOUT + n*NORD + o] = acc;
  }
}

extern "C" void kernel_launch(void* const* d_in, const int* in_sizes, int n_in,
                              void* d_out, int out_size, void* d_ws, size_t ws_size,
                              hipStream_t stream) {
  const float* x     = (const float*)d_in[0];
  const float* ev    = (const float*)d_in[1];
  const float* rbf   = (const float*)d_in[2];
  const float* ylm   = (const float*)d_in[3];
  const float* cut   = (const float*)d_in[4];
  const int*   idx_i = (const int*)d_in[5];
  const int*   idx_j = (const int*)d_in[6];
  const float* W1r   = (const float*)d_in[7];
  const float* b1r   = (const float*)d_in[8];
  const float* W2r   = (const float*)d_in[9];
  const float* b2r   = (const float*)d_in[10];
  const float* W1s   = (const float*)d_in[11];
  const float* b1s   = (const float*)d_in[12];
  const float* W2s   = (const float*)d_in[13];
  const float* b2s   = (const float*)d_in[14];
  const float* Wq    = (const float*)d_in[15];
  const float* Wk    = (const float*)d_in[16];
  const float* Wv    = (const float*)d_in[17];
  float* out = (float*)d_out;
  char* ws = (char*)d_ws;
  unsigned short* q_ws  = (unsigned short*)(ws + 0);          // 11.2 MB
  unsigned short* k_ws  = (unsigned short*)(ws + 11200000);   // 11.2 MB
  unsigned short* v_ws  = (unsigned short*)(ws + 22400000);   // 11.2 MB
  float* alpha_ws       = (float*)(ws + 33600000);            // 11.2 MB
  int* rs               = (int*)(ws + 44800000);              // 100,004 B
  unsigned short* W1sw  = (unsigned short*)(ws + 44900016);   // 28,672 B

  k_pre<<<dim3(NNODE + 1563 + 1), dim3(256), 0, stream>>>(
      x, Wq, Wk, Wv, idx_i, W1r, W1s, q_ws, k_ws, v_ws, rs, W1sw);
  k_edge<<<dim3(256), dim3(256), 0, stream>>>(
      rbf, cut, ev, idx_i, idx_j, W1sw, b1r, b1s, W2r, W2s, b2r, b2s,
      q_ws, k_ws, alpha_ws);
  k_agg<<<dim3(NNODE), dim3(256), 0, stream>>>(
      alpha_ws, v_ws, ylm, idx_j, rs, out);
}